// Round 1
// baseline (400.862 us; speedup 1.0000x reference)
//
#include <hip/hip_runtime.h>
#include <hip/hip_bf16.h>
#include <math.h>

typedef short bf16x8 __attribute__((ext_vector_type(8)));
typedef float f32x4 __attribute__((ext_vector_type(4)));

static __device__ __forceinline__ unsigned short f2bf(float f) {
  unsigned int u = __float_as_uint(f);
  u += 0x7FFFu + ((u >> 16) & 1u);
  return (unsigned short)(u >> 16);
}

// ---------------- K1: t = 2*x_tok + pe  (bf16) ----------------
// token flat order == tokenized flat order (row-major .view), so per batch
// f = m*768+d = c*262144 + n*256 + i*16 + j ; x index = (b*3+c)*262144 + ((n/32)*16+i)*512 + (n%32)*16+j
__global__ __launch_bounds__(256) void k_build_t(const float* __restrict__ x,
                                                 unsigned short* __restrict__ t) {
  int g = blockIdx.x * 256 + threadIdx.x;      // 1,572,864 threads, 8 elems each
  int f0 = g << 3;
  int bb = f0 / 786432;
  int f  = f0 - bb * 786432;
  int m  = f / 768;
  int d  = f - m * 768;
  int c  = f >> 18;
  int rl = f & 262143;
  int n  = rl >> 8;
  int qq = rl & 255;
  int ii = qq >> 4, jj = qq & 15;              // jj in {0,8}: 8 elems stay in one patch row
  const float* xp = x + ((bb * 3 + c) << 18) + (((n >> 5) << 4) + ii) * 512 + ((n & 31) << 4) + jj;
  float4 v0 = *(const float4*)xp;
  float4 v1 = *(const float4*)(xp + 4);
  float xv[8] = {v0.x, v0.y, v0.z, v0.w, v1.x, v1.y, v1.z, v1.w};
  unsigned short tmp[8];
#pragma unroll
  for (int u = 0; u < 8; ++u) {
    int dd = d + u;
    int k = dd >> 1;
    float ang = (float)m * expf(-0.023985261385f * (float)k);   // 2*ln(1e4)/768
    float pe = (dd & 1) ? cosf(ang) : sinf(ang);
    tmp[u] = f2bf(2.0f * xv[u] + pe);
  }
  *(uint4*)(t + f0) = *(const uint4*)tmp;
}

// ---------------- K2: qkv projection GEMM ----------------
// grid (36, 256): x = (h,s) so consecutive blocks reuse the same t-tile via L2;
// block = 64 rows x 64 cols, 4 waves x 16 rows, K-loop step 32, mfma 16x16x32 bf16.
__global__ __launch_bounds__(256) void k_qkv(
    const unsigned short* __restrict__ t,
    const float* __restrict__ Wq, const float* __restrict__ bq,
    const float* __restrict__ Wk, const float* __restrict__ bk,
    const float* __restrict__ Wv, const float* __restrict__ bv,
    unsigned short* __restrict__ qout, unsigned short* __restrict__ kout,
    unsigned short* __restrict__ vout) {
  __shared__ unsigned short tA[64][40];   // 64 rows x 32 k (+8 pad: 80B stride, 2-way max)
  __shared__ unsigned short tB[64][40];   // transposed W: [e][k]
  int hs = blockIdx.x;
  int rt = blockIdx.y;
  int h = hs / 3, s = hs - h * 3;
  const float* W    = (s == 0 ? Wq : (s == 1 ? Wk : Wv)) + h * 49152;
  const float* bias = (s == 0 ? bq : (s == 1 ? bk : bv)) + h * 64;
  unsigned short* outp = (s == 0 ? qout : (s == 1 ? kout : vout));
  int tid = threadIdx.x;
  int lane = tid & 63, w = tid >> 6;
  int row0 = rt << 6;
  f32x4 acc[4] = {};
  for (int k0 = 0; k0 < 768; k0 += 32) {
    __syncthreads();
#pragma unroll
    for (int it = 0; it < 2; ++it) {     // A: 64x32 bf16, ushort4 chunks
      int idx = it * 256 + tid;
      int rr = idx >> 3, kq = idx & 7;
      *(ushort4*)&tA[rr][kq << 2] =
          *(const ushort4*)(t + (row0 + rr) * 768 + k0 + (kq << 2));
    }
#pragma unroll
    for (int it = 0; it < 8; ++it) {     // B: 32x64 f32 -> bf16 transposed
      int idx = it * 256 + tid;
      int kk = idx >> 6, e = idx & 63;
      tB[e][kk] = f2bf(W[(k0 + kk) * 64 + e]);
    }
    __syncthreads();
    bf16x8 a = *(const bf16x8*)&tA[w * 16 + (lane & 15)][(lane >> 4) << 3];
#pragma unroll
    for (int cb = 0; cb < 4; ++cb) {
      bf16x8 bb = *(const bf16x8*)&tB[cb * 16 + (lane & 15)][(lane >> 4) << 3];
      acc[cb] = __builtin_amdgcn_mfma_f32_16x16x32_bf16(a, bb, acc[cb], 0, 0, 0);
    }
  }
  int rbase = row0 + w * 16 + ((lane >> 4) << 2);
#pragma unroll
  for (int cb = 0; cb < 4; ++cb) {
    int e = cb * 16 + (lane & 15);
    float bias_e = bias[e];
#pragma unroll
    for (int r = 0; r < 4; ++r) {
      int grow = rbase + r;
      int bb2 = grow >> 10, n = grow & 1023;
      outp[((bb2 * 12 + h) << 16) + (n << 6) + e] = f2bf(acc[cb][r] + bias_e);
    }
  }
}

// ---------------- K3: flash attention + untokenize scatter ----------------
__global__ __launch_bounds__(256) void k_attn(
    const unsigned short* __restrict__ Q,
    const unsigned short* __restrict__ K,
    const unsigned short* __restrict__ V,
    float* __restrict__ out) {
  __shared__ unsigned short Kt[64][72];       // [kv][e] +8 pad
  __shared__ unsigned short Vt[64][72];       // transposed: [e][kv]
  __shared__ unsigned short Pt[4][16][72];    // per-wave P tile
  int qt = blockIdx.x, h = blockIdx.y, b = blockIdx.z;
  int tid = threadIdx.x, lane = tid & 63, w = tid >> 6;
  int base = (b * 12 + h) << 16;
  const unsigned short* Qp = Q + base + (qt << 6) * 64;
  const unsigned short* Kp = K + base;
  const unsigned short* Vp = V + base;
  bf16x8 qa0 = *(const bf16x8*)(Qp + (w * 16 + (lane & 15)) * 64 + ((lane >> 4) << 3));
  bf16x8 qa1 = *(const bf16x8*)(Qp + (w * 16 + (lane & 15)) * 64 + 32 + ((lane >> 4) << 3));
  f32x4 o[4] = {};
  float mrow[4] = {-3e38f, -3e38f, -3e38f, -3e38f};
  float lrow[4] = {0.f, 0.f, 0.f, 0.f};
  for (int kv0 = 0; kv0 < 1024; kv0 += 64) {
    __syncthreads();
#pragma unroll
    for (int it = 0; it < 2; ++it) {          // K tile: 64x64 bf16, 16B chunks
      int idx = it * 256 + tid;
      *(uint4*)&Kt[idx >> 3][(idx & 7) << 3] = *(const uint4*)(Kp + (kv0 << 6) + (idx << 3));
    }
#pragma unroll
    for (int it = 0; it < 16; ++it) {         // V tile transposed (scalar)
      int idx = it * 256 + tid;
      Vt[idx & 63][idx >> 6] = Vp[(kv0 << 6) + idx];
    }
    __syncthreads();
    f32x4 s[4] = {};
#pragma unroll
    for (int cb = 0; cb < 4; ++cb) {          // S = Q K^T (16 q x 64 kv per wave)
      bf16x8 b0 = *(const bf16x8*)&Kt[cb * 16 + (lane & 15)][(lane >> 4) << 3];
      s[cb] = __builtin_amdgcn_mfma_f32_16x16x32_bf16(qa0, b0, s[cb], 0, 0, 0);
      bf16x8 b1 = *(const bf16x8*)&Kt[cb * 16 + (lane & 15)][32 + ((lane >> 4) << 3)];
      s[cb] = __builtin_amdgcn_mfma_f32_16x16x32_bf16(qa1, b1, s[cb], 0, 0, 0);
    }
    float p[4][4];
#pragma unroll
    for (int r = 0; r < 4; ++r) {             // online softmax per q-row
      float mx = fmaxf(fmaxf(s[0][r], s[1][r]), fmaxf(s[2][r], s[3][r])) * 0.125f;
      mx = fmaxf(mx, __shfl_xor(mx, 1));
      mx = fmaxf(mx, __shfl_xor(mx, 2));
      mx = fmaxf(mx, __shfl_xor(mx, 4));
      mx = fmaxf(mx, __shfl_xor(mx, 8));
      float mnew = fmaxf(mrow[r], mx);
      float sc = __expf(mrow[r] - mnew);
      mrow[r] = mnew;
      float rs = 0.f;
#pragma unroll
      for (int cb = 0; cb < 4; ++cb) {
        float pv = __expf(s[cb][r] * 0.125f - mnew);
        p[cb][r] = pv;
        rs += pv;
      }
      rs += __shfl_xor(rs, 1);
      rs += __shfl_xor(rs, 2);
      rs += __shfl_xor(rs, 4);
      rs += __shfl_xor(rs, 8);
      lrow[r] = lrow[r] * sc + rs;
      o[0][r] *= sc; o[1][r] *= sc; o[2][r] *= sc; o[3][r] *= sc;
    }
#pragma unroll
    for (int r = 0; r < 4; ++r)               // P -> LDS (per-wave, no barrier needed)
#pragma unroll
      for (int cb = 0; cb < 4; ++cb)
        Pt[w][((lane >> 4) << 2) + r][cb * 16 + (lane & 15)] = f2bf(p[cb][r]);
#pragma unroll
    for (int kk = 0; kk < 2; ++kk) {          // O += P V
      bf16x8 pa = *(const bf16x8*)&Pt[w][lane & 15][kk * 32 + ((lane >> 4) << 3)];
#pragma unroll
      for (int cb = 0; cb < 4; ++cb) {
        bf16x8 vb = *(const bf16x8*)&Vt[cb * 16 + (lane & 15)][kk * 32 + ((lane >> 4) << 3)];
        o[cb] = __builtin_amdgcn_mfma_f32_16x16x32_bf16(pa, vb, o[cb], 0, 0, 0);
      }
    }
  }
#pragma unroll
  for (int cb = 0; cb < 4; ++cb) {            // epilogue: /l, concat-heads + untokenize
#pragma unroll
    for (int r = 0; r < 4; ++r) {
      int m = (qt << 6) + w * 16 + ((lane >> 4) << 2) + r;
      int d = (h << 6) + cb * 16 + (lane & 15);
      int f = m * 768 + d;
      int c = f >> 18, rl = f & 262143, n = rl >> 8, qq = rl & 255;
      out[((b * 3 + c) << 18) + (((n >> 5) << 4) + (qq >> 4)) * 512 + ((n & 31) << 4) + (qq & 15)] =
          o[cb][r] / lrow[r];
    }
  }
}

extern "C" void kernel_launch(void* const* d_in, const int* in_sizes, int n_in,
                              void* d_out, int out_size, void* d_ws, size_t ws_size,
                              hipStream_t stream) {
  const float* x  = (const float*)d_in[0];
  const float* Wq = (const float*)d_in[1];
  const float* bq = (const float*)d_in[2];
  const float* Wk = (const float*)d_in[3];
  const float* bk = (const float*)d_in[4];
  const float* Wv = (const float*)d_in[5];
  const float* bv = (const float*)d_in[6];
  float* out = (float*)d_out;
  unsigned short* t  = (unsigned short*)d_ws;       // 16*1024*768 bf16 = 25.2 MB
  unsigned short* qw = t  + 12582912;               // (b,h,n,e) bf16, 25.2 MB
  unsigned short* kw = qw + 12582912;
  unsigned short* vw = kw + 12582912;
  k_build_t<<<6144, 256, 0, stream>>>(x, t);
  k_qkv<<<dim3(36, 256), 256, 0, stream>>>(t, Wq, bq, Wk, bk, Wv, bv, qw, kw, vw);
  k_attn<<<dim3(16, 12, 16), 256, 0, stream>>>(qw, kw, vw, out);
}

// Round 2
// 306.875 us; speedup vs baseline: 1.3063x; 1.3063x over previous
//
#include <hip/hip_runtime.h>
#include <hip/hip_bf16.h>
#include <math.h>

typedef short bf16x8 __attribute__((ext_vector_type(8)));
typedef float f32x4 __attribute__((ext_vector_type(4)));

static __device__ __forceinline__ unsigned short f2bf(float f) {
  unsigned int u = __float_as_uint(f);
  u += 0x7FFFu + ((u >> 16) & 1u);
  return (unsigned short)(u >> 16);
}

// ---------------- K0: W (f32 [h][k][e]) -> bf16 transposed wt[s][h][e][k] ----------------
__global__ __launch_bounds__(256) void k_prep_w(const float* __restrict__ Wq,
                                                const float* __restrict__ Wk,
                                                const float* __restrict__ Wv,
                                                unsigned short* __restrict__ wt) {
  __shared__ unsigned short lw[64][72];
  int sh = blockIdx.x;                    // s*12+h
  int kt = blockIdx.y;                    // 64-wide k tile
  int s = sh / 12, h = sh - s * 12;
  const float* W = (s == 0 ? Wq : (s == 1 ? Wk : Wv)) + h * 49152 + (kt << 6) * 64;
  int tid = threadIdx.x;
#pragma unroll
  for (int it = 0; it < 4; ++it) {        // 64k x 64e f32, coalesced float4
    int idx = it * 256 + tid;
    int kk = idx >> 4, e4 = (idx & 15) << 2;
    float4 v = *(const float4*)(W + kk * 64 + e4);
    lw[e4 + 0][kk] = f2bf(v.x);
    lw[e4 + 1][kk] = f2bf(v.y);
    lw[e4 + 2][kk] = f2bf(v.z);
    lw[e4 + 3][kk] = f2bf(v.w);
  }
  __syncthreads();
  unsigned short* outp = wt + sh * 49152 + (kt << 6);
#pragma unroll
  for (int it = 0; it < 2; ++it) {        // write [e][k] rows, uint4 coalesced
    int c = it * 256 + tid;
    int e = c >> 3, kc = (c & 7) << 3;
    *(uint4*)(outp + e * 768 + kc) = *(const uint4*)&lw[e][kc];
  }
}

// ---------------- K1: t = 2*x_tok + pe  (bf16) ----------------
__global__ __launch_bounds__(256) void k_build_t(const float* __restrict__ x,
                                                 unsigned short* __restrict__ t) {
  int g = blockIdx.x * 256 + threadIdx.x;
  int f0 = g << 3;
  int bb = f0 / 786432;
  int f  = f0 - bb * 786432;
  int m  = f / 768;
  int d  = f - m * 768;
  int c  = f >> 18;
  int rl = f & 262143;
  int n  = rl >> 8;
  int qq = rl & 255;
  int ii = qq >> 4, jj = qq & 15;
  const float* xp = x + ((bb * 3 + c) << 18) + (((n >> 5) << 4) + ii) * 512 + ((n & 31) << 4) + jj;
  float4 v0 = *(const float4*)xp;
  float4 v1 = *(const float4*)(xp + 4);
  float xv[8] = {v0.x, v0.y, v0.z, v0.w, v1.x, v1.y, v1.z, v1.w};
  unsigned short tmp[8];
#pragma unroll
  for (int u = 0; u < 8; ++u) {
    int dd = d + u;
    int k = dd >> 1;
    float ang = (float)m * expf(-0.023985261385f * (float)k);
    float pe = (dd & 1) ? cosf(ang) : sinf(ang);
    tmp[u] = f2bf(2.0f * xv[u] + pe);
  }
  *(uint4*)(t + f0) = *(const uint4*)tmp;
}

// ---------------- K2: qkv projection GEMM (128-row blocks) ----------------
union SMQKV {
  struct { unsigned short tA[128][40]; unsigned short tB[64][40]; } g;
  unsigned short tr[64][136];             // V-transpose staging (272B rows, 16B aligned)
};
__global__ __launch_bounds__(256) void k_qkv(
    const unsigned short* __restrict__ t, const unsigned short* __restrict__ wt,
    const float* __restrict__ bq, const float* __restrict__ bk, const float* __restrict__ bv,
    unsigned short* __restrict__ qout, unsigned short* __restrict__ kout,
    unsigned short* __restrict__ vout) {
  __shared__ SMQKV sm;
  int hs = blockIdx.x;                    // h*3+s
  int rt = blockIdx.y;
  int h = hs / 3, s = hs - h * 3;
  const unsigned short* Wp = wt + (s * 12 + h) * 49152;
  const float* bias = (s == 0 ? bq : (s == 1 ? bk : bv)) + h * 64;
  unsigned short* outp = (s == 0 ? qout : (s == 1 ? kout : vout));
  int tid = threadIdx.x, lane = tid & 63, w = tid >> 6;
  int row0 = rt << 7;
  f32x4 acc[2][4] = {};
  for (int k0 = 0; k0 < 768; k0 += 32) {
    __syncthreads();
#pragma unroll
    for (int it = 0; it < 2; ++it) {      // A: 128x32 bf16
      int idx = it * 256 + tid;
      int rr = idx >> 2, kq = (idx & 3) << 3;
      *(uint4*)&sm.g.tA[rr][kq] = *(const uint4*)(t + (row0 + rr) * 768 + k0 + kq);
    }
    {                                     // B: 64x32 bf16 from wt
      int e = tid >> 2, kc = (tid & 3) << 3;
      *(uint4*)&sm.g.tB[e][kc] = *(const uint4*)(Wp + e * 768 + k0 + kc);
    }
    __syncthreads();
    bf16x8 a0 = *(const bf16x8*)&sm.g.tA[w * 32 + (lane & 15)][(lane >> 4) << 3];
    bf16x8 a1 = *(const bf16x8*)&sm.g.tA[w * 32 + 16 + (lane & 15)][(lane >> 4) << 3];
#pragma unroll
    for (int cb = 0; cb < 4; ++cb) {
      bf16x8 bb = *(const bf16x8*)&sm.g.tB[cb * 16 + (lane & 15)][(lane >> 4) << 3];
      acc[0][cb] = __builtin_amdgcn_mfma_f32_16x16x32_bf16(a0, bb, acc[0][cb], 0, 0, 0);
      acc[1][cb] = __builtin_amdgcn_mfma_f32_16x16x32_bf16(a1, bb, acc[1][cb], 0, 0, 0);
    }
  }
  int bb2 = row0 >> 10;
  int n0 = row0 & 1023;
  int base = (bb2 * 12 + h) << 16;
  if (s < 2) {
    float qs = (s == 0) ? 0.125f : 1.0f;  // fold 1/sqrt(dh) into q
#pragma unroll
    for (int mt = 0; mt < 2; ++mt)
#pragma unroll
      for (int cb = 0; cb < 4; ++cb) {
        int e = cb * 16 + (lane & 15);
        float be = bias[e];
#pragma unroll
        for (int r = 0; r < 4; ++r) {
          int n = n0 + w * 32 + mt * 16 + ((lane >> 4) << 2) + r;
          outp[base + (n << 6) + e] = f2bf((acc[mt][cb][r] + be) * qs);
        }
      }
  } else {                                // V: store transposed [b][h][e][n]
    __syncthreads();
#pragma unroll
    for (int mt = 0; mt < 2; ++mt)
#pragma unroll
      for (int cb = 0; cb < 4; ++cb) {
        int e = cb * 16 + (lane & 15);
        float be = bias[e];
#pragma unroll
        for (int r = 0; r < 4; ++r) {
          int rr = w * 32 + mt * 16 + ((lane >> 4) << 2) + r;
          sm.tr[e][rr] = f2bf(acc[mt][cb][r] + be);
        }
      }
    __syncthreads();
#pragma unroll
    for (int it = 0; it < 4; ++it) {      // 64 e-rows x 128 n, uint4 coalesced
      int c = it * 256 + tid;
      int e = c >> 4, nc = (c & 15) << 3;
      *(uint4*)(vout + base + (e << 10) + n0 + nc) = *(const uint4*)&sm.tr[e][nc];
    }
  }
}

// ---------------- K3: flash attention + untokenize scatter ----------------
__global__ __launch_bounds__(256) void k_attn(
    const unsigned short* __restrict__ Q,
    const unsigned short* __restrict__ K,
    const unsigned short* __restrict__ Vg,   // transposed [b][h][e][n]
    float* __restrict__ out) {
  __shared__ unsigned short Kt[64][72];      // [kv][e]
  __shared__ unsigned short Vt[64][72];      // [e][kv]
  __shared__ unsigned short Pt[4][32][72];   // per-wave P
  int qt = blockIdx.x, h = blockIdx.y, b = blockIdx.z;
  int tid = threadIdx.x, lane = tid & 63, w = tid >> 6;
  int base = (b * 12 + h) << 16;
  const unsigned short* Qp = Q + base + (qt << 7) * 64;
  const unsigned short* Kp = K + base;
  const unsigned short* Vp = Vg + base;
  bf16x8 qa[2][2];
#pragma unroll
  for (int mt = 0; mt < 2; ++mt)
#pragma unroll
    for (int kf = 0; kf < 2; ++kf)
      qa[mt][kf] = *(const bf16x8*)(Qp + (w * 32 + mt * 16 + (lane & 15)) * 64 +
                                    kf * 32 + ((lane >> 4) << 3));
  f32x4 o[2][4] = {};
  float mrow[2][4], lrow[2][4] = {};
#pragma unroll
  for (int mt = 0; mt < 2; ++mt)
#pragma unroll
    for (int r = 0; r < 4; ++r) mrow[mt][r] = -3e38f;
  for (int kv0 = 0; kv0 < 1024; kv0 += 64) {
    __syncthreads();
#pragma unroll
    for (int it = 0; it < 2; ++it) {      // K + V^T tiles, uint4 coalesced
      int idx = it * 256 + tid;
      int rr = idx >> 3, cc = (idx & 7) << 3;
      *(uint4*)&Kt[rr][cc] = *(const uint4*)(Kp + (kv0 << 6) + (idx << 3));
      *(uint4*)&Vt[rr][cc] = *(const uint4*)(Vp + (rr << 10) + kv0 + cc);
    }
    __syncthreads();
    f32x4 s[2][4] = {};
#pragma unroll
    for (int cb = 0; cb < 4; ++cb) {      // S = Q K^T (scale pre-folded into Q)
      bf16x8 b0 = *(const bf16x8*)&Kt[cb * 16 + (lane & 15)][(lane >> 4) << 3];
      bf16x8 b1 = *(const bf16x8*)&Kt[cb * 16 + (lane & 15)][32 + ((lane >> 4) << 3)];
#pragma unroll
      for (int mt = 0; mt < 2; ++mt) {
        s[mt][cb] = __builtin_amdgcn_mfma_f32_16x16x32_bf16(qa[mt][0], b0, s[mt][cb], 0, 0, 0);
        s[mt][cb] = __builtin_amdgcn_mfma_f32_16x16x32_bf16(qa[mt][1], b1, s[mt][cb], 0, 0, 0);
      }
    }
#pragma unroll
    for (int mt = 0; mt < 2; ++mt)
#pragma unroll
      for (int r = 0; r < 4; ++r) {       // online softmax, wave-parallel
        float mx = fmaxf(fmaxf(s[mt][0][r], s[mt][1][r]), fmaxf(s[mt][2][r], s[mt][3][r]));
        mx = fmaxf(mx, __shfl_xor(mx, 1));
        mx = fmaxf(mx, __shfl_xor(mx, 2));
        mx = fmaxf(mx, __shfl_xor(mx, 4));
        mx = fmaxf(mx, __shfl_xor(mx, 8));
        float mnew = fmaxf(mrow[mt][r], mx);
        float sc = __expf(mrow[mt][r] - mnew);
        mrow[mt][r] = mnew;
        float rs = 0.f;
        int prow = mt * 16 + ((lane >> 4) << 2) + r;
#pragma unroll
        for (int cb = 0; cb < 4; ++cb) {
          float pv = __expf(s[mt][cb][r] - mnew);
          rs += pv;
          Pt[w][prow][cb * 16 + (lane & 15)] = f2bf(pv);
        }
        rs += __shfl_xor(rs, 1);
        rs += __shfl_xor(rs, 2);
        rs += __shfl_xor(rs, 4);
        rs += __shfl_xor(rs, 8);
        lrow[mt][r] = lrow[mt][r] * sc + rs;
#pragma unroll
        for (int cb = 0; cb < 4; ++cb) o[mt][cb][r] *= sc;
      }
#pragma unroll
    for (int kk = 0; kk < 2; ++kk) {      // O += P V
      bf16x8 vb[4];
#pragma unroll
      for (int cb = 0; cb < 4; ++cb)
        vb[cb] = *(const bf16x8*)&Vt[cb * 16 + (lane & 15)][kk * 32 + ((lane >> 4) << 3)];
#pragma unroll
      for (int mt = 0; mt < 2; ++mt) {
        bf16x8 pa = *(const bf16x8*)&Pt[w][mt * 16 + (lane & 15)][kk * 32 + ((lane >> 4) << 3)];
#pragma unroll
        for (int cb = 0; cb < 4; ++cb)
          o[mt][cb] = __builtin_amdgcn_mfma_f32_16x16x32_bf16(pa, vb[cb], o[mt][cb], 0, 0, 0);
      }
    }
  }
#pragma unroll
  for (int mt = 0; mt < 2; ++mt)          // epilogue: /l, concat-heads + untokenize
#pragma unroll
    for (int cb = 0; cb < 4; ++cb)
#pragma unroll
      for (int r = 0; r < 4; ++r) {
        int m = (qt << 7) + w * 32 + mt * 16 + ((lane >> 4) << 2) + r;
        int d = (h << 6) + cb * 16 + (lane & 15);
        int f = m * 768 + d;
        int c = f >> 18, rl = f & 262143, n = rl >> 8, qq = rl & 255;
        out[((b * 3 + c) << 18) + (((n >> 5) << 4) + (qq >> 4)) * 512 + ((n & 31) << 4) + (qq & 15)] =
            o[mt][cb][r] / lrow[mt][r];
      }
}

extern "C" void kernel_launch(void* const* d_in, const int* in_sizes, int n_in,
                              void* d_out, int out_size, void* d_ws, size_t ws_size,
                              hipStream_t stream) {
  const float* x  = (const float*)d_in[0];
  const float* Wq = (const float*)d_in[1];
  const float* bq = (const float*)d_in[2];
  const float* Wk = (const float*)d_in[3];
  const float* bk = (const float*)d_in[4];
  const float* Wv = (const float*)d_in[5];
  const float* bv = (const float*)d_in[6];
  float* out = (float*)d_out;
  unsigned short* wt = (unsigned short*)d_ws;       // 3*12*64*768 bf16 = 3.5 MB
  unsigned short* t  = wt + 1769472;                // 16*1024*768 bf16 = 25.2 MB
  unsigned short* qw = t  + 12582912;
  unsigned short* kw = qw + 12582912;
  unsigned short* vw = kw + 12582912;               // transposed [b][h][e][n]
  k_prep_w<<<dim3(36, 12), 256, 0, stream>>>(Wq, Wk, Wv, wt);
  k_build_t<<<6144, 256, 0, stream>>>(x, t);
  k_qkv<<<dim3(36, 128), 256, 0, stream>>>(t, wt, bq, bk, bv, qw, kw, vw);
  k_attn<<<dim3(8, 12, 16), 256, 0, stream>>>(qw, kw, vw, out);
}

// Round 5
// 225.134 us; speedup vs baseline: 1.7806x; 1.3631x over previous
//
#include <hip/hip_runtime.h>
#include <hip/hip_bf16.h>
#include <math.h>

typedef short bf16x8 __attribute__((ext_vector_type(8)));
typedef float f32x4 __attribute__((ext_vector_type(4)));

static __device__ __forceinline__ unsigned short f2bf(float f) {
  unsigned int u = __float_as_uint(f);
  u += 0x7FFFu + ((u >> 16) & 1u);
  return (unsigned short)(u >> 16);
}

// ---------------- K0: W (f32 [h][k][e]) -> bf16 transposed wt[s][h][e][k] ----------------
__global__ __launch_bounds__(256) void k_prep_w(const float* __restrict__ Wq,
                                                const float* __restrict__ Wk,
                                                const float* __restrict__ Wv,
                                                unsigned short* __restrict__ wt) {
  __shared__ unsigned short lw[64][72];
  int sh = blockIdx.x;
  int kt = blockIdx.y;
  int s = sh / 12, h = sh - s * 12;
  const float* W = (s == 0 ? Wq : (s == 1 ? Wk : Wv)) + h * 49152 + (kt << 6) * 64;
  int tid = threadIdx.x;
#pragma unroll
  for (int it = 0; it < 4; ++it) {
    int idx = it * 256 + tid;
    int kk = idx >> 4, e4 = (idx & 15) << 2;
    float4 v = *(const float4*)(W + kk * 64 + e4);
    lw[e4 + 0][kk] = f2bf(v.x);
    lw[e4 + 1][kk] = f2bf(v.y);
    lw[e4 + 2][kk] = f2bf(v.z);
    lw[e4 + 3][kk] = f2bf(v.w);
  }
  __syncthreads();
  unsigned short* outp = wt + sh * 49152 + (kt << 6);
#pragma unroll
  for (int it = 0; it < 2; ++it) {
    int c = it * 256 + tid;
    int e = c >> 3, kc = (c & 7) << 3;
    *(uint4*)(outp + e * 768 + kc) = *(const uint4*)&lw[e][kc];
  }
}

// ---------------- K1: t = 2*x_tok + pe (bf16); PE computed once, reused over 16 batches ----
__global__ __launch_bounds__(256) void k_build_t(const float* __restrict__ x,
                                                 unsigned short* __restrict__ t) {
  int g = blockIdx.x * 256 + threadIdx.x;      // 98304 threads, 8 elems x 16 batches
  int f = g << 3;
  int m  = f / 768;
  int d  = f - m * 768;
  int c  = f >> 18;
  int rl = f & 262143;
  int n  = rl >> 8;
  int qq = rl & 255;
  int ii = qq >> 4, jj = qq & 15;
  float pe8[8];
#pragma unroll
  for (int u = 0; u < 8; ++u) {
    int dd = d + u;
    int k = dd >> 1;
    float ang = (float)m * expf(-0.023985261385f * (float)k);
    pe8[u] = (dd & 1) ? cosf(ang) : sinf(ang);
  }
  const float* xp0 = x + (c << 18) + (((n >> 5) << 4) + ii) * 512 + ((n & 31) << 4) + jj;
  for (int b = 0; b < 16; ++b) {
    const float* xp = xp0 + b * 786432;
    float4 v0 = *(const float4*)xp;
    float4 v1 = *(const float4*)(xp + 4);
    float xv[8] = {v0.x, v0.y, v0.z, v0.w, v1.x, v1.y, v1.z, v1.w};
    unsigned short tmp[8];
#pragma unroll
    for (int u = 0; u < 8; ++u) tmp[u] = f2bf(2.0f * xv[u] + pe8[u]);
    *(uint4*)(t + b * 786432 + f) = *(const uint4*)tmp;
  }
}

// ---------------- K2: qkv projection GEMM (128-row blocks, XCD-swizzled) ----------------
union SMQKV {
  struct { unsigned short tA[128][40]; unsigned short tB[64][40]; } g;
  unsigned short tr[64][136];
};
__global__ __launch_bounds__(256) void k_qkv(
    const unsigned short* __restrict__ t, const unsigned short* __restrict__ wt,
    const float* __restrict__ bq, const float* __restrict__ bk, const float* __restrict__ bv,
    unsigned short* __restrict__ qout, unsigned short* __restrict__ kout,
    unsigned short* __restrict__ vout) {
  __shared__ SMQKV sm;
  int bid = blockIdx.x;                   // 4608 blocks; same-rt blocks co-XCD
  int xcd = bid & 7, idx = bid >> 3;
  int rt = xcd * 16 + idx / 36;
  int hs = idx % 36;
  int h = hs / 3, s = hs - h * 3;
  const unsigned short* Wp = wt + (s * 12 + h) * 49152;
  const float* bias = (s == 0 ? bq : (s == 1 ? bk : bv)) + h * 64;
  unsigned short* outp = (s == 0 ? qout : (s == 1 ? kout : vout));
  int tid = threadIdx.x, lane = tid & 63, w = tid >> 6;
  int row0 = rt << 7;
  f32x4 acc[2][4] = {};
  for (int k0 = 0; k0 < 768; k0 += 32) {
    __syncthreads();
#pragma unroll
    for (int it = 0; it < 2; ++it) {
      int idx2 = it * 256 + tid;
      int rr = idx2 >> 2, kq = (idx2 & 3) << 3;
      *(uint4*)&sm.g.tA[rr][kq] = *(const uint4*)(t + (row0 + rr) * 768 + k0 + kq);
    }
    {
      int e = tid >> 2, kc = (tid & 3) << 3;
      *(uint4*)&sm.g.tB[e][kc] = *(const uint4*)(Wp + e * 768 + k0 + kc);
    }
    __syncthreads();
    bf16x8 a0 = *(const bf16x8*)&sm.g.tA[w * 32 + (lane & 15)][(lane >> 4) << 3];
    bf16x8 a1 = *(const bf16x8*)&sm.g.tA[w * 32 + 16 + (lane & 15)][(lane >> 4) << 3];
#pragma unroll
    for (int cb = 0; cb < 4; ++cb) {
      bf16x8 bb = *(const bf16x8*)&sm.g.tB[cb * 16 + (lane & 15)][(lane >> 4) << 3];
      acc[0][cb] = __builtin_amdgcn_mfma_f32_16x16x32_bf16(a0, bb, acc[0][cb], 0, 0, 0);
      acc[1][cb] = __builtin_amdgcn_mfma_f32_16x16x32_bf16(a1, bb, acc[1][cb], 0, 0, 0);
    }
  }
  int bb2 = row0 >> 10;
  int n0 = row0 & 1023;
  int base = (bb2 * 12 + h) << 16;
  if (s < 2) {
    // q: fold 1/sqrt(64) * log2(e) so attention works in exp2 domain
    float qs = (s == 0) ? 0.18033688011f : 1.0f;
#pragma unroll
    for (int mt = 0; mt < 2; ++mt)
#pragma unroll
      for (int cb = 0; cb < 4; ++cb) {
        int e = cb * 16 + (lane & 15);
        float be = bias[e];
#pragma unroll
        for (int r = 0; r < 4; ++r) {
          int n = n0 + w * 32 + mt * 16 + ((lane >> 4) << 2) + r;
          outp[base + (n << 6) + e] = f2bf((acc[mt][cb][r] + be) * qs);
        }
      }
  } else {
    // V: store transposed [b][h][e][n], with kv-index PERMUTED within each 32-block:
    // position p holds original o where p(o) = ((o>>2)&3)*8 + ((o>>4)&1)*4 + (o&3).
    // This makes k_attn's P-registers directly usable as the PV A-fragment (no shuffles).
    __syncthreads();
#pragma unroll
    for (int mt = 0; mt < 2; ++mt)
#pragma unroll
      for (int cb = 0; cb < 4; ++cb) {
        int e = cb * 16 + (lane & 15);
        float be = bias[e];
#pragma unroll
        for (int r = 0; r < 4; ++r) {
          int rr = w * 32 + ((lane >> 4) << 3) + mt * 4 + r;   // permuted position
          sm.tr[e][rr] = f2bf(acc[mt][cb][r] + be);
        }
      }
    __syncthreads();
#pragma unroll
    for (int it = 0; it < 4; ++it) {
      int c = it * 256 + tid;
      int e = c >> 4, nc = (c & 15) << 3;
      *(uint4*)(vout + base + (e << 10) + n0 + nc) = *(const uint4*)&sm.tr[e][nc];
    }
  }
}

// ---------------- K3: flash attention, swapped QK^T + in-register softmax ----------------
__global__ __launch_bounds__(256) void k_attn(
    const unsigned short* __restrict__ Q,
    const unsigned short* __restrict__ K,
    const unsigned short* __restrict__ Vg,   // transposed+permuted [b][h][e][n']
    float* __restrict__ out) {
  __shared__ unsigned short Kt[64][72];      // [kv][k]
  __shared__ unsigned short Vt[80][72];      // [e][kv']; rows 64..79: ones-column block
  int bid = blockIdx.x;                      // 1536 blocks; same-(b,h) co-XCD
  int xcd = bid & 7, idx = bid >> 3;
  int bh = xcd * 24 + (idx >> 3);
  int qt = idx & 7;
  int b = bh / 12, h = bh - b * 12;
  int tid = threadIdx.x, lane = tid & 63, w = tid >> 6;
  int g = lane >> 4, q16 = lane & 15;
  int base = bh << 16;
  const unsigned short* Qp = Q + base + (qt << 7) * 64;
  const unsigned short* Kp = K + base;
  const unsigned short* Vp = Vg + base;
  {                                          // ones-column block init (once)
    int rr = 64 + (tid >> 4), c4 = (tid & 15) << 2;
    ushort4 z = {0, 0, 0, 0};
    if ((tid >> 4) == 0) { z.x = z.y = z.z = z.w = 0x3F80; }
    *(ushort4*)&Vt[rr][c4] = z;
  }
  bf16x8 qa[2][2];
#pragma unroll
  for (int mt = 0; mt < 2; ++mt)
#pragma unroll
    for (int kf = 0; kf < 2; ++kf)
      qa[mt][kf] = *(const bf16x8*)(Qp + (w * 32 + mt * 16 + q16) * 64 + kf * 32 + (g << 3));
  f32x4 o[2][5] = {};                        // cb=4 accumulates row-sums (l)
  float mrow[2] = {-1e30f, -1e30f};
  for (int kv0 = 0; kv0 < 1024; kv0 += 64) {
    __syncthreads();
#pragma unroll
    for (int it = 0; it < 2; ++it) {
      int idx2 = it * 256 + tid;
      int rr = idx2 >> 3, cc = (idx2 & 7) << 3;
      *(uint4*)&Kt[rr][cc] = *(const uint4*)(Kp + (kv0 << 6) + (idx2 << 3));
      *(uint4*)&Vt[rr][cc] = *(const uint4*)(Vp + (rr << 10) + kv0 + cc);
    }
    __syncthreads();
    // S^T = K Q^T : lane owns q=q16, kv = cb*16 + g*4 + r
    f32x4 s[2][4] = {};
#pragma unroll
    for (int cb = 0; cb < 4; ++cb) {
      bf16x8 ka0 = *(const bf16x8*)&Kt[cb * 16 + q16][g << 3];
      bf16x8 ka1 = *(const bf16x8*)&Kt[cb * 16 + q16][32 + (g << 3)];
#pragma unroll
      for (int mt = 0; mt < 2; ++mt) {
        s[mt][cb] = __builtin_amdgcn_mfma_f32_16x16x32_bf16(ka0, qa[mt][0], s[mt][cb], 0, 0, 0);
        s[mt][cb] = __builtin_amdgcn_mfma_f32_16x16x32_bf16(ka1, qa[mt][1], s[mt][cb], 0, 0, 0);
      }
    }
    // row max (15 fmax + 2 shfl), defer-max rescale
    float pmax[2];
#pragma unroll
    for (int mt = 0; mt < 2; ++mt) {
      float mx = s[mt][0][0];
#pragma unroll
      for (int cb = 0; cb < 4; ++cb)
#pragma unroll
        for (int r = 0; r < 4; ++r) mx = fmaxf(mx, s[mt][cb][r]);
      mx = fmaxf(mx, __shfl_xor(mx, 16));
      mx = fmaxf(mx, __shfl_xor(mx, 32));
      pmax[mt] = mx;
    }
    if (__any((pmax[0] > mrow[0] + 8.f) || (pmax[1] > mrow[1] + 8.f))) {
#pragma unroll
      for (int mt = 0; mt < 2; ++mt) {
        float mnew = fmaxf(mrow[mt], pmax[mt]);
        float sc = __builtin_amdgcn_exp2f(mrow[mt] - mnew);
        mrow[mt] = mnew;
#pragma unroll
        for (int r = 0; r < 4; ++r) {
          float scr = __shfl(sc, (g << 2) + r);   // map softmax-domain -> o-domain rows
#pragma unroll
          for (int cb = 0; cb < 5; ++cb) o[mt][cb][r] *= scr;
        }
      }
    }
    // P = exp2(s - m), packed to bf16 pairs in-register
    unsigned int pk[2][4][2];
#pragma unroll
    for (int mt = 0; mt < 2; ++mt)
#pragma unroll
      for (int cb = 0; cb < 4; ++cb)
#pragma unroll
        for (int j2 = 0; j2 < 2; ++j2) {
          float plo = __builtin_amdgcn_exp2f(s[mt][cb][2 * j2] - mrow[mt]);
          float phi = __builtin_amdgcn_exp2f(s[mt][cb][2 * j2 + 1] - mrow[mt]);
          asm("v_cvt_pk_bf16_f32 %0, %1, %2" : "=v"(pk[mt][cb][j2]) : "v"(plo), "v"(phi));
        }
    // O += P V : V's kv-order is permuted so lane's own pk registers ARE the A-fragment
#pragma unroll
    for (int kk = 0; kk < 2; ++kk) {
      union { unsigned int u[4]; bf16x8 v; } pa[2];
#pragma unroll
      for (int mt = 0; mt < 2; ++mt) {
        pa[mt].u[0] = pk[mt][2 * kk][0];
        pa[mt].u[1] = pk[mt][2 * kk][1];
        pa[mt].u[2] = pk[mt][2 * kk + 1][0];
        pa[mt].u[3] = pk[mt][2 * kk + 1][1];
      }
#pragma unroll
      for (int cb = 0; cb < 5; ++cb) {
        bf16x8 vb = *(const bf16x8*)&Vt[cb * 16 + q16][kk * 32 + (g << 3)];
#pragma unroll
        for (int mt = 0; mt < 2; ++mt)
          o[mt][cb] = __builtin_amdgcn_mfma_f32_16x16x32_bf16(pa[mt].v, vb, o[mt][cb], 0, 0, 0);
      }
    }
  }
  // epilogue: l = o[.][4] (col 64), broadcast within 4-lane group; scatter untokenized
#pragma unroll
  for (int mt = 0; mt < 2; ++mt)
#pragma unroll
    for (int r = 0; r < 4; ++r) {
      float lr = __shfl(o[mt][4][r], lane & 48);
      float inv = 1.0f / lr;
      int m = (qt << 7) + w * 32 + mt * 16 + (g << 2) + r;
#pragma unroll
      for (int cb = 0; cb < 4; ++cb) {
        int d = (h << 6) + cb * 16 + q16;
        int f = m * 768 + d;
        int c = f >> 18, rl = f & 262143, n = rl >> 8, qq = rl & 255;
        out[((b * 3 + c) << 18) + (((n >> 5) << 4) + (qq >> 4)) * 512 + ((n & 31) << 4) + (qq & 15)] =
            o[mt][cb][r] * inv;
      }
    }
}

extern "C" void kernel_launch(void* const* d_in, const int* in_sizes, int n_in,
                              void* d_out, int out_size, void* d_ws, size_t ws_size,
                              hipStream_t stream) {
  const float* x  = (const float*)d_in[0];
  const float* Wq = (const float*)d_in[1];
  const float* bq = (const float*)d_in[2];
  const float* Wk = (const float*)d_in[3];
  const float* bk = (const float*)d_in[4];
  const float* Wv = (const float*)d_in[5];
  const float* bv = (const float*)d_in[6];
  float* out = (float*)d_out;
  unsigned short* wt = (unsigned short*)d_ws;
  unsigned short* t  = wt + 1769472;
  unsigned short* qw = t  + 12582912;
  unsigned short* kw = qw + 12582912;
  unsigned short* vw = kw + 12582912;
  k_prep_w<<<dim3(36, 12), 256, 0, stream>>>(Wq, Wk, Wv, wt);
  k_build_t<<<384, 256, 0, stream>>>(x, t);
  k_qkv<<<4608, 256, 0, stream>>>(t, wt, bq, bk, bv, qw, kw, vw);
  k_attn<<<1536, 256, 0, stream>>>(qw, kw, vw, out);
}